// Round 2
// baseline (498.669 us; speedup 1.0000x reference)
//
#include <hip/hip_runtime.h>
#include <math.h>

// Problem constants (fixed by reference):
//   x: [B=32, C=512, H=64, W=64] fp32; HW = 4096
//   fc1_w: [64, 768], fc1_b: [64], fc2_w: [1,64], fc2_b: [1]
// Algebraic collapse (harness-verified in round 0, absmax 3.9e-3):
//   xc[b,c]  = mean_{hw} x[b,c,hw]
//   q[b,m]   = mean(xc[b,4m..4m+3])                       (m < 128)
//   s[b,c,h] = relu(T1[b,h] + xc[b,c]*T2[b,h] + fc1_b[h])
//     T1[b,h] = sum_f xc[b,f] * w[h,f]                     (f < 512)
//     T2[b,h] = sum_m q[b,m] * (w[h,512+m] + w[h,640+m])   (m < 128)
//   a[b,c]   = sigmoid(fc2_b + sum_h fc2_w[h]*s[b,c,h])
//   out      = x * a[b,c]
//
// Structure (round 2): NO cooperative launch (not graph-capturable — round-1
// failure). Two plain kernels; K2 replicates the tiny attention math per block
// (weights L2-resident) instead of synchronizing on it.

#define B_  32
#define C_  512
#define HW_ 4096
#define ROWS_ (B_ * C_)   // 16384

typedef float f32x4 __attribute__((ext_vector_type(4)));

// ---------------- K1: wave-per-row spatial mean ----------------
// 4096 blocks x 256 threads; each wave owns one row (64 lanes x 16 float4).
__global__ __launch_bounds__(256) void k_rowmean(const float* __restrict__ x,
                                                 float* __restrict__ xc) {
    const int lane = threadIdx.x & 63;
    const int wave = threadIdx.x >> 6;
    const int row  = blockIdx.x * 4 + wave;
    const f32x4* xr = (const f32x4*)(x + (size_t)row * HW_);
    float s = 0.f;
#pragma unroll
    for (int j = 0; j < 16; ++j) {
        f32x4 v = xr[lane + j * 64];
        s += (v[0] + v[1]) + (v[2] + v[3]);
    }
#pragma unroll
    for (int off = 32; off > 0; off >>= 1) s += __shfl_down(s, off, 64);
    if (lane == 0) xc[row] = s * (1.0f / (float)HW_);
}

// ---------------- K2: fused attention + scale ----------------
// 1024 blocks x 256 threads. Block i owns 16 consecutive rows, mapped in
// REVERSE order vs K1's read stream so K2's first reads hit the L3-resident
// tail of K1's pass (x is exactly L3-sized, 256 MiB).
// Each block recomputes its batch's attention scalars locally (tiny).
__global__ __launch_bounds__(256) void k_att_scale(
        const float* __restrict__ x,
        const float* __restrict__ xc,
        const float* __restrict__ fc1w,
        const float* __restrict__ fc1b,
        const float* __restrict__ fc2w,
        const float* __restrict__ fc2b,
        float* __restrict__ out) {
    const int tid = threadIdx.x;
    const int row_lo = ROWS_ - (int)(blockIdx.x + 1) * 16;  // 16 rows, one batch
    const int b  = row_lo / C_;
    const int c0 = row_lo % C_;

    __shared__ float xcs[C_];
    __shared__ float qs[128];
    __shared__ float p1[256], p2[256];
    __shared__ float s1[64], s2[64], w2s[64];
    __shared__ float as[16];

    // load xc row (512 floats) + fc2 weights
    xcs[tid]       = xc[b * C_ + tid];
    xcs[tid + 256] = xc[b * C_ + 256 + tid];
    if (tid < 64) w2s[tid] = fc2w[tid];
    __syncthreads();

    if (tid < 128) {
        qs[tid] = (xcs[4 * tid] + xcs[4 * tid + 1] +
                   xcs[4 * tid + 2] + xcs[4 * tid + 3]) * 0.25f;
    }
    __syncthreads();

    // T1[h], T2[h]: 4 partial threads per h (weights stay L2-resident
    // across the 1024 blocks; ~196 KiB per XCD of real fetch)
    {
        const int h = tid & 63, part = tid >> 6;
        const float* w = fc1w + h * 768;
        float t1 = 0.f, t2 = 0.f;
        const int f0 = part * 128;
#pragma unroll 8
        for (int f = 0; f < 128; ++f) t1 += xcs[f0 + f] * w[f0 + f];
        const int m0 = part * 32;
#pragma unroll 8
        for (int m = 0; m < 32; ++m)
            t2 += qs[m0 + m] * (w[512 + m0 + m] + w[640 + m0 + m]);
        p1[tid] = t1;
        p2[tid] = t2;
    }
    __syncthreads();
    if (tid < 64) {
        s1[tid] = (p1[tid] + p1[tid + 64]) + (p1[tid + 128] + p1[tid + 192]) + fc1b[tid];
        s2[tid] = (p2[tid] + p2[tid + 64]) + (p2[tid + 128] + p2[tid + 192]);
    }
    __syncthreads();

    // a for this block's 16 channels only (no global a round-trip)
    if (tid < 16) {
        const float xv = xcs[c0 + tid];
        float acc = fc2b[0];
#pragma unroll 8
        for (int hh = 0; hh < 64; ++hh) {
            float z = s1[hh] + xv * s2[hh];
            acc += w2s[hh] * (z > 0.f ? z : 0.f);
        }
        as[tid] = 1.0f / (1.0f + __expf(-acc));
    }
    __syncthreads();

    // scale: wave w handles rows 4w..4w+3; NT stores keep x resident in L3
    const int lane = tid & 63, wave = tid >> 6;
#pragma unroll
    for (int r = 0; r < 4; ++r) {
        const int ri  = wave * 4 + r;           // 0..15
        const int row = row_lo + ri;
        const float sc = as[ri];
        const f32x4* xr  = (const f32x4*)(x + (size_t)row * HW_);
        f32x4* outr      = (f32x4*)(out + (size_t)row * HW_);
#pragma unroll
        for (int j = 0; j < 16; ++j) {
            f32x4 v = xr[lane + j * 64];
            v *= sc;
            __builtin_nontemporal_store(v, &outr[lane + j * 64]);
        }
    }
}

extern "C" void kernel_launch(void* const* d_in, const int* in_sizes, int n_in,
                              void* d_out, int out_size, void* d_ws, size_t ws_size,
                              hipStream_t stream) {
    const float* x     = (const float*)d_in[0];
    const float* fc1_w = (const float*)d_in[1];
    const float* fc1_b = (const float*)d_in[2];
    const float* fc2_w = (const float*)d_in[3];
    const float* fc2_b = (const float*)d_in[4];
    float* out = (float*)d_out;

    float* xc = (float*)d_ws;  // ROWS_ floats

    k_rowmean<<<ROWS_ / 4, 256, 0, stream>>>(x, xc);
    k_att_scale<<<ROWS_ / 16, 256, 0, stream>>>(x, xc, fc1_w, fc1_b, fc2_w, fc2_b, out);
}